// Round 1
// baseline (1762.993 us; speedup 1.0000x reference)
//
#include <hip/hip_runtime.h>
#include <cstdint>
#include <cstddef>

#define NB 128      // N
#define KPP 32      // Kp
#define VV 2048     // V
#define SS 200      // S (tm1)
#define WID 32      // width == K
#define NCAND (KPP*VV + KPP)   // 65568

// output layout (flat f32, concat in return order)
#define O_YNEXT  ((size_t)0)
#define SZ_YNEXT ((size_t)(SS+1)*NB*WID)               // 823296
#define NK       ((size_t)NB*WID)                      // 4096
#define O_LAST   (SZ_YNEXT)
#define O_LENS   (SZ_YNEXT + NK)
#define O_NB     (SZ_YNEXT + 2*NK)
#define O_B      (SZ_YNEXT + 3*NK)
#define O_PREF   (SZ_YNEXT + 4*NK)                     // size NB*WID*WID = 131072
#define O_SRC    (SZ_YNEXT + 4*NK + (size_t)NB*WID*WID)
#define O_NOEXT  (SZ_YNEXT + 5*NK + (size_t)NB*WID*WID)

__device__ __forceinline__ unsigned fkey(float f) {
    unsigned u = __float_as_uint(f);
    return (u & 0x80000000u) ? ~u : (u | 0x80000000u);
}
__device__ __forceinline__ float funkey(unsigned k) {
    unsigned u = (k & 0x80000000u) ? (k & 0x7FFFFFFFu) : ~k;
    return __uint_as_float(u);
}
__device__ __forceinline__ unsigned long long shflx64(unsigned long long v, int m) {
    int lo = __shfl_xor((int)(unsigned)v, m);
    int hi = __shfl_xor((int)(unsigned)(v >> 32), m);
    return ((unsigned long long)(unsigned)hi << 32) | (unsigned)lo;
}

__global__ __launch_bounds__(1024) void select_kernel(
    const float* __restrict__ ext,     // [N][Kp][V]
    const float* __restrict__ nonext,  // [N][V]
    const float* __restrict__ blank,   // [N]
    const float* __restrict__ nbp_g,   // [N][Kp]
    const float* __restrict__ bp_g,    // [N][Kp]
    const int*   __restrict__ yprev,   // [S][N][Kp]
    const int*   __restrict__ ylast,   // [N][Kp]
    const int*   __restrict__ ylens,   // [N][Kp]
    const int*   __restrict__ pip,     // [N][Kp][Kp]
    float* __restrict__ out)
{
    const int n   = blockIdx.x;
    const int tid = threadIdx.x;
    const int lane = tid & 63;
    const int wid  = tid >> 6;

    __shared__ int      s_last[KPP];
    __shared__ float    s_nbp[KPP], s_bp[KPP], s_bne[KPP], s_nbne[KPP];
    __shared__ int      s_tm[KPP][KPP];
    __shared__ unsigned s_exact[KPP];
    __shared__ unsigned s_hm[KPP][VV/32];        // 8KB has_match bitmask
    __shared__ unsigned long long s_wbest[16];
    __shared__ unsigned long long s_winner;
    __shared__ int      s_selidx[WID];
    __shared__ float    s_selval[WID];

    // ---- prep phase ----
    for (int i = tid; i < KPP*(VV/32); i += 1024) ((unsigned*)s_hm)[i] = 0u;
    if (tid < KPP) {
        int k = tid;
        s_exact[k] = 0u;
        int last = ylast[n*KPP + k];
        last = min(max(last, 0), VV-1);
        float a = nbp_g[n*KPP + k], b = bp_g[n*KPP + k];
        s_last[k] = last; s_nbp[k] = a; s_bp[k] = b;
        s_bne[k]  = (a + b) * blank[n];
        s_nbne[k] = a * nonext[(size_t)n*VV + last];
    }
    __syncthreads();

    {   // to_match + ext_is_exact: one thread per (k,j)
        int k = tid >> 5, j = tid & 31;
        int tlen = ylens[n*KPP + k];
        int tcl  = min(max(tlen, 0), SS-1);
        int tm   = yprev[((size_t)tcl*NB + n)*KPP + j];
        tm = min(max(tm, 0), VV-1);
        s_tm[k][j] = tm;
        bool ex = (ylens[n*KPP + k] + 1 == ylens[n*KPP + j]) && (pip[((size_t)n*KPP + k)*KPP + j] != 0);
        if (ex) {
            atomicOr(&s_exact[k], 1u << j);
            atomicOr(&s_hm[k][tm >> 5], 1u << (tm & 31));
        }
    }
    __syncthreads();

    if (tid < KPP) {    // absorb into nb_nonext (deterministic k-order sum)
        int j = tid;
        float acc = s_nbne[j];
        for (int k = 0; k < KPP; ++k) {
            if ((s_exact[k] >> j) & 1u) {
                int v = s_tm[k][j];
                float base = (v == s_last[k]) ? 0.0f : s_nbp[k];
                acc += (base + s_bp[k]) * ext[((size_t)n*KPP + k)*VV + v];
            }
        }
        s_nbne[j] = acc;
    }
    __syncthreads();

    // ---- candidate scan (on the fly) ----
    auto candval = [&](int idx) -> float {
        if (idx < KPP*VV) {
            int k = idx >> 11, v = idx & (VV-1);
            if ((s_hm[k][v >> 5] >> (v & 31)) & 1u) return -INFINITY;
            float base = (v == s_last[k]) ? 0.0f : s_nbp[k];
            return (base + s_bp[k]) * ext[((size_t)n*KPP + k)*VV + v];
        } else {
            int k = idx - KPP*VV;
            return s_nbne[k] + s_bne[k];
        }
    };

    unsigned long long best = 0ull;
    #pragma unroll 4
    for (int i = 0; i < (NCAND + 1023)/1024; ++i) {
        int idx = tid + i*1024;
        if (idx < NCAND) {
            float v = candval(idx);
            unsigned long long p = ((unsigned long long)fkey(v) << 32) | (unsigned)(~idx);
            if (p > best) best = p;
        }
    }
    {   // wave reduce -> s_wbest
        unsigned long long wb = best;
        for (int off = 32; off; off >>= 1) {
            unsigned long long o = shflx64(wb, off);
            if (o > wb) wb = o;
        }
        if (lane == 0) s_wbest[wid] = wb;
    }
    __syncthreads();

    // ---- 32 extraction rounds ----
    for (int r = 0; r < WID; ++r) {
        if (tid == 0) {
            unsigned long long w = 0ull;
            for (int q = 0; q < 16; ++q) { unsigned long long c = s_wbest[q]; if (c > w) w = c; }
            s_winner = w;
            s_selidx[r] = (int)(~(unsigned)w);
            s_selval[r] = funkey((unsigned)(w >> 32));
        }
        __syncthreads();
        int widx  = (int)(~(unsigned)s_winner);
        int owner = widx & 1023;
        if (tid == owner) {   // rescan my chunk excluding all selected
            best = 0ull;
            for (int i = 0; i < (NCAND + 1023)/1024; ++i) {
                int idx = tid + i*1024;
                if (idx < NCAND) {
                    bool sel = false;
                    for (int q = 0; q <= r; ++q) sel |= (s_selidx[q] == idx);
                    if (!sel) {
                        float v = candval(idx);
                        unsigned long long p = ((unsigned long long)fkey(v) << 32) | (unsigned)(~idx);
                        if (p > best) best = p;
                    }
                }
            }
        }
        if (wid == (owner >> 6)) {  // owner wave refreshes its cached max
            unsigned long long wb = best;
            for (int off = 32; off; off >>= 1) {
                unsigned long long o = shflx64(wb, off);
                if (o > wb) wb = o;
            }
            if (lane == 0) s_wbest[wid] = wb;
        }
        __syncthreads();
    }

    // ---- epilogue: per-k scalar outputs ----
    if (tid < WID) {
        int k = tid;
        int ind = s_selidx[k];
        bool noext = ind >= KPP*VV;
        int src  = noext ? (ind - KPP*VV) : (ind >> 11);
        int extk = ind & (VV-1);                  // == ind % V (matches ref for both paths)
        int plen = ylens[n*KPP + src];
        int lens = plen + (noext ? 0 : 1);
        float nbv = noext ? s_nbne[src] : s_selval[k];
        float bv  = noext ? s_bne[src]  : 0.0f;
        int lastv = noext ? s_last[src] : extk;
        size_t o = (size_t)n*WID + k;
        out[O_LAST  + o] = (float)lastv;
        out[O_LENS  + o] = (float)lens;
        out[O_NB    + o] = nbv;
        out[O_B     + o] = bv;
        out[O_SRC   + o] = (float)src;
        out[O_NOEXT + o] = noext ? 1.0f : 0.0f;
    }
}

__global__ void ynext_kernel(const int* __restrict__ yprev, float* __restrict__ out) {
    int id = blockIdx.x*blockDim.x + threadIdx.x;
    if (id >= (int)SZ_YNEXT) return;
    int k = id & 31;
    int n = (id >> 5) & 127;
    int t = id >> 12;                    // NB*WID = 4096 = 2^12
    size_t o = (size_t)n*WID + k;
    int src    = (int)out[O_SRC + o];
    bool noext = out[O_NOEXT + o] != 0.0f;
    int lens   = (int)out[O_LENS + o];
    int plen   = lens - (noext ? 0 : 1);
    int extk   = noext ? src : (int)out[O_LAST + o];
    float val;
    if (t == plen)      val = (float)extk;
    else if (t < SS)    val = (float)yprev[((size_t)t*NB + n)*KPP + src];
    else                val = 0.0f;
    out[id] = val;
}

__global__ void prefix_kernel(const int* __restrict__ yprev, const int* __restrict__ pip,
                              float* __restrict__ out) {
    int id = blockIdx.x*blockDim.x + threadIdx.x;   // N*32*32
    if (id >= NB*WID*WID) return;
    int j = id & 31;
    int k = (id >> 5) & 31;
    int n = id >> 10;
    size_t ok = (size_t)n*WID + k, oj = (size_t)n*WID + j;
    int  src_k = (int)out[O_SRC + ok];
    int  src_j = (int)out[O_SRC + oj];
    bool no_k  = out[O_NOEXT + ok] != 0.0f;
    bool no_j  = out[O_NOEXT + oj] != 0.0f;
    int  lens_k = (int)out[O_LENS + ok];
    int  lens_j = (int)out[O_LENS + oj];
    int  ext_k = no_k ? src_k : (int)out[O_LAST + ok];
    int  ext_j = no_j ? src_j : (int)out[O_LAST + oj];
    int  plen_j = lens_j - (no_j ? 0 : 1);
    bool prefix = pip[((size_t)n*KPP + src_k)*KPP + src_j] != 0;
    bool leq    = lens_k <= lens_j;
    int  tstar  = max(lens_k - 1, 0);
    int  tmj;
    if (tstar == plen_j)   tmj = ext_j;
    else if (tstar < SS)   tmj = yprev[((size_t)tstar*NB + n)*KPP + src_j];
    else                   tmj = 0;
    bool matches = (tmj == ext_k);
    bool res = prefix && leq && (no_k || matches);
    out[O_PREF + (size_t)n*WID*WID + (size_t)k*WID + j] = res ? 1.0f : 0.0f;
}

extern "C" void kernel_launch(void* const* d_in, const int* in_sizes, int n_in,
                              void* d_out, int out_size, void* d_ws, size_t ws_size,
                              hipStream_t stream) {
    const float* ext    = (const float*)d_in[0];
    const float* nonext = (const float*)d_in[1];
    const float* blank  = (const float*)d_in[2];
    const float* nbp    = (const float*)d_in[3];
    const float* bp     = (const float*)d_in[4];
    const int*   yprev  = (const int*)d_in[5];
    const int*   ylast  = (const int*)d_in[6];
    const int*   ylens  = (const int*)d_in[7];
    const int*   pip    = (const int*)d_in[8];
    float* out = (float*)d_out;

    select_kernel<<<NB, 1024, 0, stream>>>(ext, nonext, blank, nbp, bp,
                                           yprev, ylast, ylens, pip, out);
    ynext_kernel<<<((int)SZ_YNEXT + 255)/256, 256, 0, stream>>>(yprev, out);
    prefix_kernel<<<(NB*WID*WID + 255)/256, 256, 0, stream>>>(yprev, pip, out);
}

// Round 2
// 169.087 us; speedup vs baseline: 10.4265x; 10.4265x over previous
//
#include <hip/hip_runtime.h>
#include <cstdint>
#include <cstddef>

#define NB 128      // N
#define KPP 32      // Kp
#define VV 2048     // V
#define SS 200      // S (tm1)
#define WID 32      // width == K
#define NEXT_BASE (KPP*VV)     // 65536

// output layout (flat f32, concat in return order)
#define O_YNEXT  ((size_t)0)
#define SZ_YNEXT ((size_t)(SS+1)*NB*WID)               // 823296
#define NK       ((size_t)NB*WID)                      // 4096
#define O_LAST   (SZ_YNEXT)
#define O_LENS   (SZ_YNEXT + NK)
#define O_NB     (SZ_YNEXT + 2*NK)
#define O_B      (SZ_YNEXT + 3*NK)
#define O_PREF   (SZ_YNEXT + 4*NK)                     // size NB*WID*WID = 131072
#define O_SRC    (SZ_YNEXT + 4*NK + (size_t)NB*WID*WID)
#define O_NOEXT  (SZ_YNEXT + 5*NK + (size_t)NB*WID*WID)

__device__ __forceinline__ unsigned fkey(float f) {
    unsigned u = __float_as_uint(f);
    return (u & 0x80000000u) ? ~u : (u | 0x80000000u);
}
__device__ __forceinline__ float funkey(unsigned k) {
    unsigned u = (k & 0x80000000u) ? (k & 0x7FFFFFFFu) : ~k;
    return __uint_as_float(u);
}

__global__ __launch_bounds__(1024) void select_kernel(
    const float* __restrict__ ext,     // [N][Kp][V]
    const float* __restrict__ nonext,  // [N][V]
    const float* __restrict__ blank,   // [N]
    const float* __restrict__ nbp_g,   // [N][Kp]
    const float* __restrict__ bp_g,    // [N][Kp]
    const int*   __restrict__ yprev,   // [S][N][Kp]
    const int*   __restrict__ ylast,   // [N][Kp]
    const int*   __restrict__ ylens,   // [N][Kp]
    const int*   __restrict__ pip,     // [N][Kp][Kp]
    float* __restrict__ out)
{
    const int n    = blockIdx.x;
    const int tid  = threadIdx.x;
    const int lane = tid & 63;
    const int wid  = tid >> 6;

    __shared__ int      s_last[KPP];
    __shared__ float    s_nbp[KPP], s_bp[KPP], s_bne[KPP], s_nbne[KPP];
    __shared__ int      s_tm[KPP][KPP];
    __shared__ unsigned s_exact[KPP];
    __shared__ unsigned s_hm[KPP][VV/32];        // 8KB has_match bitmask
    __shared__ int      s_part[2][16];
    __shared__ int      s_cnt;
    __shared__ unsigned s_slot_f[WID];
    __shared__ int      s_slot_i[WID];
    __shared__ int      s_selidx[WID];
    __shared__ float    s_selval[WID];

    // ---- prep phase ----
    for (int i = tid; i < KPP*(VV/32); i += 1024) ((unsigned*)s_hm)[i] = 0u;
    if (tid == 0) s_cnt = 0;
    if (tid < KPP) {
        int k = tid;
        s_exact[k] = 0u;
        int last = ylast[n*KPP + k];
        last = min(max(last, 0), VV-1);
        float a = nbp_g[n*KPP + k], b = bp_g[n*KPP + k];
        s_last[k] = last; s_nbp[k] = a; s_bp[k] = b;
        s_bne[k]  = (a + b) * blank[n];
        s_nbne[k] = a * nonext[(size_t)n*VV + last];
    }
    __syncthreads();

    if (tid < KPP*KPP) {   // to_match + ext_is_exact: one thread per (k,j)
        int k = tid >> 5, j = tid & 31;
        int tlen = ylens[n*KPP + k];
        int tcl  = min(max(tlen, 0), SS-1);
        int tm   = yprev[((size_t)tcl*NB + n)*KPP + j];
        tm = min(max(tm, 0), VV-1);
        s_tm[k][j] = tm;
        bool ex = (ylens[n*KPP + k] + 1 == ylens[n*KPP + j]) && (pip[((size_t)n*KPP + k)*KPP + j] != 0);
        if (ex) {
            atomicOr(&s_exact[k], 1u << j);
            atomicOr(&s_hm[k][tm >> 5], 1u << (tm & 31));
        }
    }
    __syncthreads();

    if (tid < KPP) {    // absorb into nb_nonext (deterministic k-order sum)
        int j = tid;
        float acc = s_nbne[j];
        for (int k = 0; k < KPP; ++k) {
            if ((s_exact[k] >> j) & 1u) {
                int v = s_tm[k][j];
                float base = (v == s_last[k]) ? 0.0f : s_nbp[k];
                acc += (base + s_bp[k]) * ext[((size_t)n*KPP + k)*VV + v];
            }
        }
        s_nbne[j] = acc;
    }
    __syncthreads();

    // ---- phase 1: compute & cache candidate fkeys in registers ----
    // ext candidates: idx = tid + i*1024, i in [0,64)  (64*1024 == Kp*V exactly)
    // nonext candidates: idx = 65536 + tid for tid < 32
    const float* extn = ext + (size_t)n*KPP*VV;
    unsigned k32[64];
    #pragma unroll
    for (int i = 0; i < 64; ++i) {
        int idx = tid + (i << 10);
        int k = idx >> 11, v = idx & (VV-1);
        float base = (v == s_last[k]) ? 0.0f : s_nbp[k];
        float val = (base + s_bp[k]) * extn[idx];
        if ((s_hm[k][v >> 5] >> (v & 31)) & 1u) val = -INFINITY;
        k32[i] = fkey(val);
    }
    const bool has_n = (tid < KPP);
    unsigned kn = has_n ? fkey(s_nbne[tid] + s_bne[tid]) : 0u;

    int pp = 0;
    auto blockSum = [&](int v) -> int {
        #pragma unroll
        for (int off = 32; off; off >>= 1) v += __shfl_xor(v, off);
        if (lane == 0) s_part[pp][wid] = v;
        __syncthreads();
        int tot = 0;
        #pragma unroll
        for (int q = 0; q < 16; ++q) tot += s_part[pp][q];
        pp ^= 1;
        return tot;
    };

    // ---- stage 1: radix select on fkey (find 32nd-largest value T) ----
    unsigned prefix = 0u;
    int need = WID;
    int mc = 64 + (has_n ? 1 : 0);   // my candidates still matching prefix
    for (int b = 31; b >= 0; --b) {
        int c1 = 0;
        if (__any(mc != 0)) {
            unsigned pb1 = (prefix >> b) | 1u;
            #pragma unroll
            for (int i = 0; i < 64; ++i) c1 += ((k32[i] >> b) == pb1) ? 1 : 0;
            if (has_n) c1 += ((kn >> b) == pb1) ? 1 : 0;
        }
        int tot = blockSum(c1);
        if (tot >= need) { prefix |= (1u << b); mc = c1; }
        else             { need -= tot;         mc -= c1; }
    }
    const unsigned T = prefix;

    // ---- stage 2: select `need` smallest idx among ties (fkey == T) ----
    unsigned long long alive = 0ull;
    #pragma unroll
    for (int i = 0; i < 64; ++i)
        alive |= ((unsigned long long)(k32[i] == T ? 1 : 0)) << i;
    bool alive_n = has_n && (kn == T);
    unsigned istar = 0u;
    #pragma unroll
    for (int b = 16; b >= 0; --b) {
        unsigned long long zm;   // mask over slots i whose idx-bit b == 0
        bool nz;                 // nonext candidate's idx-bit b == 0 ?
        if      (b == 16) { zm = ~0ull;                     nz = false; }
        else if (b == 15) { zm = 0x00000000FFFFFFFFull;     nz = true; }
        else if (b == 14) { zm = 0x0000FFFF0000FFFFull;     nz = true; }
        else if (b == 13) { zm = 0x00FF00FF00FF00FFull;     nz = true; }
        else if (b == 12) { zm = 0x0F0F0F0F0F0F0F0Full;     nz = true; }
        else if (b == 11) { zm = 0x3333333333333333ull;     nz = true; }
        else if (b == 10) { zm = 0x5555555555555555ull;     nz = true; }
        else { bool t0 = (((tid >> b) & 1) == 0); zm = t0 ? ~0ull : 0ull; nz = t0; }
        int c0 = __popcll(alive & zm) + ((alive_n && nz) ? 1 : 0);
        int tot0 = blockSum(c0);
        if (tot0 >= need) { alive &= zm;  alive_n = alive_n && nz; }
        else { need -= tot0; alive &= ~zm; alive_n = alive_n && !nz; istar |= (1u << b); }
    }

    // ---- gather the exact 32 selected (kk > T, or kk == T && idx <= I*) ----
    #pragma unroll
    for (int i = 0; i < 64; ++i) {
        unsigned kk = k32[i];
        int idx = tid + (i << 10);
        if (kk > T || (kk == T && (unsigned)idx <= istar)) {
            int slot = atomicAdd(&s_cnt, 1);
            s_slot_f[slot] = kk; s_slot_i[slot] = idx;
        }
    }
    if (has_n) {
        int idx = NEXT_BASE + tid;
        if (kn > T || (kn == T && (unsigned)idx <= istar)) {
            int slot = atomicAdd(&s_cnt, 1);
            s_slot_f[slot] = kn; s_slot_i[slot] = idx;
        }
    }
    __syncthreads();

    // ---- rank-sort the 32 selected: values desc, idx asc within ties ----
    if (tid < WID) {
        unsigned mf = s_slot_f[tid]; int mi = s_slot_i[tid];
        unsigned long long mk = ((unsigned long long)mf << 32) | (unsigned)(~mi);
        int rank = 0;
        for (int j = 0; j < WID; ++j) {
            unsigned long long kj = ((unsigned long long)s_slot_f[j] << 32) | (unsigned)(~s_slot_i[j]);
            rank += (kj > mk) ? 1 : 0;
        }
        s_selidx[rank] = mi;
        s_selval[rank] = funkey(mf);
    }
    __syncthreads();

    // ---- epilogue: per-k scalar outputs ----
    if (tid < WID) {
        int k = tid;
        int ind = s_selidx[k];
        bool noext = ind >= NEXT_BASE;
        int src  = noext ? (ind - NEXT_BASE) : (ind >> 11);
        int extk = ind & (VV-1);
        int plen = ylens[n*KPP + src];
        int lens = plen + (noext ? 0 : 1);
        float nbv = noext ? s_nbne[src] : s_selval[k];
        float bv  = noext ? s_bne[src]  : 0.0f;
        int lastv = noext ? s_last[src] : extk;
        size_t o = (size_t)n*WID + k;
        out[O_LAST  + o] = (float)lastv;
        out[O_LENS  + o] = (float)lens;
        out[O_NB    + o] = nbv;
        out[O_B     + o] = bv;
        out[O_SRC   + o] = (float)src;
        out[O_NOEXT + o] = noext ? 1.0f : 0.0f;
    }
}

__global__ void ynext_kernel(const int* __restrict__ yprev, float* __restrict__ out) {
    int id = blockIdx.x*blockDim.x + threadIdx.x;
    if (id >= (int)SZ_YNEXT) return;
    int k = id & 31;
    int n = (id >> 5) & 127;
    int t = id >> 12;                    // NB*WID = 4096 = 2^12
    size_t o = (size_t)n*WID + k;
    int src    = (int)out[O_SRC + o];
    bool noext = out[O_NOEXT + o] != 0.0f;
    int lens   = (int)out[O_LENS + o];
    int plen   = lens - (noext ? 0 : 1);
    int extk   = noext ? src : (int)out[O_LAST + o];
    float val;
    if (t == plen)      val = (float)extk;
    else if (t < SS)    val = (float)yprev[((size_t)t*NB + n)*KPP + src];
    else                val = 0.0f;
    out[id] = val;
}

__global__ void prefix_kernel(const int* __restrict__ yprev, const int* __restrict__ pip,
                              float* __restrict__ out) {
    int id = blockIdx.x*blockDim.x + threadIdx.x;   // N*32*32
    if (id >= NB*WID*WID) return;
    int j = id & 31;
    int k = (id >> 5) & 31;
    int n = id >> 10;
    size_t ok = (size_t)n*WID + k, oj = (size_t)n*WID + j;
    int  src_k = (int)out[O_SRC + ok];
    int  src_j = (int)out[O_SRC + oj];
    bool no_k  = out[O_NOEXT + ok] != 0.0f;
    bool no_j  = out[O_NOEXT + oj] != 0.0f;
    int  lens_k = (int)out[O_LENS + ok];
    int  lens_j = (int)out[O_LENS + oj];
    int  ext_k = no_k ? src_k : (int)out[O_LAST + ok];
    int  ext_j = no_j ? src_j : (int)out[O_LAST + oj];
    int  plen_j = lens_j - (no_j ? 0 : 1);
    bool prefix = pip[((size_t)n*KPP + src_k)*KPP + src_j] != 0;
    bool leq    = lens_k <= lens_j;
    int  tstar  = max(lens_k - 1, 0);
    int  tmj;
    if (tstar == plen_j)   tmj = ext_j;
    else if (tstar < SS)   tmj = yprev[((size_t)tstar*NB + n)*KPP + src_j];
    else                   tmj = 0;
    bool matches = (tmj == ext_k);
    bool res = prefix && leq && (no_k || matches);
    out[O_PREF + (size_t)n*WID*WID + (size_t)k*WID + j] = res ? 1.0f : 0.0f;
}

extern "C" void kernel_launch(void* const* d_in, const int* in_sizes, int n_in,
                              void* d_out, int out_size, void* d_ws, size_t ws_size,
                              hipStream_t stream) {
    const float* ext    = (const float*)d_in[0];
    const float* nonext = (const float*)d_in[1];
    const float* blank  = (const float*)d_in[2];
    const float* nbp    = (const float*)d_in[3];
    const float* bp     = (const float*)d_in[4];
    const int*   yprev  = (const int*)d_in[5];
    const int*   ylast  = (const int*)d_in[6];
    const int*   ylens  = (const int*)d_in[7];
    const int*   pip    = (const int*)d_in[8];
    float* out = (float*)d_out;

    select_kernel<<<NB, 1024, 0, stream>>>(ext, nonext, blank, nbp, bp,
                                           yprev, ylast, ylens, pip, out);
    ynext_kernel<<<((int)SZ_YNEXT + 255)/256, 256, 0, stream>>>(yprev, out);
    prefix_kernel<<<(NB*WID*WID + 255)/256, 256, 0, stream>>>(yprev, pip, out);
}

// Round 3
// 118.115 us; speedup vs baseline: 14.9261x; 1.4315x over previous
//
#include <hip/hip_runtime.h>
#include <cstdint>
#include <cstddef>

#define NB 128      // N
#define KPP 32      // Kp
#define VV 2048     // V
#define SS 200      // S (tm1)
#define WID 32      // width == K
#define NEXT_BASE (KPP*VV)     // 65536
#define CAP 2048               // survivor-list capacity

// output layout (flat f32, concat in return order)
#define SZ_YNEXT ((size_t)(SS+1)*NB*WID)               // 823296
#define NK       ((size_t)NB*WID)                      // 4096
#define O_LAST   (SZ_YNEXT)
#define O_LENS   (SZ_YNEXT + NK)
#define O_NB     (SZ_YNEXT + 2*NK)
#define O_B      (SZ_YNEXT + 3*NK)
#define O_PREF   (SZ_YNEXT + 4*NK)                     // size NB*WID*WID
#define O_SRC    (SZ_YNEXT + 4*NK + (size_t)NB*WID*WID)
#define O_NOEXT  (SZ_YNEXT + 5*NK + (size_t)NB*WID*WID)

__device__ __forceinline__ unsigned fkey(float f) {
    unsigned u = __float_as_uint(f);
    return (u & 0x80000000u) ? ~u : (u | 0x80000000u);
}
__device__ __forceinline__ float funkey(unsigned k) {
    unsigned u = (k & 0x80000000u) ? (k & 0x7FFFFFFFu) : ~k;
    return __uint_as_float(u);
}

__global__ __launch_bounds__(1024) void ctc_fused_kernel(
    const float* __restrict__ ext,     // [N][Kp][V]
    const float* __restrict__ nonext,  // [N][V]
    const float* __restrict__ blank,   // [N]
    const float* __restrict__ nbp_g,   // [N][Kp]
    const float* __restrict__ bp_g,    // [N][Kp]
    const int*   __restrict__ yprev,   // [S][N][Kp]
    const int*   __restrict__ ylast,   // [N][Kp]
    const int*   __restrict__ ylens,   // [N][Kp]
    const int*   __restrict__ pip,     // [N][Kp][Kp]
    float* __restrict__ out)
{
    const int n    = blockIdx.x;
    const int tid  = threadIdx.x;
    const int lane = tid & 63;
    const int wid  = tid >> 6;

    __shared__ int      s_last[KPP];
    __shared__ float    s_nbp[KPP], s_bp[KPP], s_bne[KPP], s_nbne[KPP];
    __shared__ int      s_tm[KPP][KPP];
    __shared__ unsigned s_exact[KPP];
    __shared__ unsigned s_hm[KPP][VV/32];        // 8KB has_match bitmask
    __shared__ unsigned s_hist[16][256];         // per-wave histograms (16KB)
    __shared__ unsigned s_bins[256];
    __shared__ int      s_bstar, s_G;
    __shared__ int      s_part[2][16];
    __shared__ int      s_cnt;
    __shared__ unsigned s_lf[CAP];
    __shared__ int      s_li[CAP];
    __shared__ int      s_selidx[WID];
    __shared__ float    s_selval[WID];
    __shared__ int      s_r_src[WID], s_r_lens[WID], s_r_ext[WID], s_r_noext[WID], s_r_last[WID];

    // ---- prep phase ----
    for (int i = tid; i < KPP*(VV/32); i += 1024) ((unsigned*)s_hm)[i] = 0u;
    if (tid == 0) s_cnt = 0;
    if (tid < KPP) {
        int k = tid;
        s_exact[k] = 0u;
        int last = ylast[n*KPP + k];
        last = min(max(last, 0), VV-1);
        float a = nbp_g[n*KPP + k], b = bp_g[n*KPP + k];
        s_last[k] = last; s_nbp[k] = a; s_bp[k] = b;
        s_bne[k]  = (a + b) * blank[n];
        s_nbne[k] = a * nonext[(size_t)n*VV + last];
    }
    __syncthreads();

    {   // to_match + ext_is_exact: one thread per (k,j)
        int k = tid >> 5, j = tid & 31;
        int tlen = ylens[n*KPP + k];
        int tcl  = min(max(tlen, 0), SS-1);
        int tm   = yprev[((size_t)tcl*NB + n)*KPP + j];
        tm = min(max(tm, 0), VV-1);
        s_tm[k][j] = tm;
        bool ex = (ylens[n*KPP + k] + 1 == ylens[n*KPP + j]) && (pip[((size_t)n*KPP + k)*KPP + j] != 0);
        if (ex) {
            atomicOr(&s_exact[k], 1u << j);
            atomicOr(&s_hm[k][tm >> 5], 1u << (tm & 31));
        }
    }
    __syncthreads();

    if (tid < KPP) {    // absorb into nb_nonext (deterministic k-order sum)
        int j = tid;
        float acc = s_nbne[j];
        for (int k = 0; k < KPP; ++k) {
            if ((s_exact[k] >> j) & 1u) {
                int v = s_tm[k][j];
                float base = (v == s_last[k]) ? 0.0f : s_nbp[k];
                acc += (base + s_bp[k]) * ext[((size_t)n*KPP + k)*VV + v];
            }
        }
        s_nbne[j] = acc;
    }
    __syncthreads();

    const float* extn = ext + (size_t)n*KPP*VV;

    // candidate key for slot i (idx = i*1024 + tid): k = i>>1 (compile-time), v = (i&1)*1024 + tid
#define CAND_KEY(i, kk)  {                                                    \
        const int k_ = (i) >> 1;                                              \
        const int v_ = (((i) & 1) << 10) + tid;                               \
        float base_ = (v_ == s_last[k_]) ? 0.0f : s_nbp[k_];                  \
        float val_  = (base_ + s_bp[k_]) * extn[((i) << 10) + tid];           \
        if ((s_hm[k_][v_ >> 5] >> (v_ & 31)) & 1u) val_ = -INFINITY;          \
        kk = fkey(val_); }

    // ---- histogram-cascade select: find prefix containing the 32nd-largest ----
    unsigned pref = 0;
    int shift = 32;          // unresolved low bits; match iff (kk >> shift) == pref
    int need = WID;
    int gt_base = 0;
    int c = 0;

    for (int lvl = 0; lvl < 4; ++lvl) {
        for (int i = tid; i < 16*256; i += 1024) ((unsigned*)s_hist)[i] = 0u;
        __syncthreads();
        unsigned* myh = s_hist[wid];
        #pragma unroll
        for (int i = 0; i < 64; ++i) {
            unsigned kk; CAND_KEY(i, kk);
            if (lvl == 0 || (kk >> shift) == pref)
                atomicAdd(&myh[(kk >> (shift - 8)) & 255], 1u);
        }
        if (tid < KPP) {
            unsigned kk = fkey(s_nbne[tid] + s_bne[tid]);
            if (lvl == 0 || (kk >> shift) == pref)
                atomicAdd(&myh[(kk >> (shift - 8)) & 255], 1u);
        }
        __syncthreads();
        if (tid < 256) {
            unsigned s = 0;
            #pragma unroll
            for (int w = 0; w < 16; ++w) s += s_hist[w][tid];
            s_bins[tid] = s;
        }
        __syncthreads();
        if (tid < 256) {   // unique b*: G(b*) < need <= G(b*) + bins[b*]
            int g = 0;
            for (int b = tid + 1; b < 256; ++b) g += (int)s_bins[b];
            if (g < need && g + (int)s_bins[tid] >= need) { s_bstar = tid; s_G = g; }
        }
        __syncthreads();
        int bstar = s_bstar, G = s_G;
        int bcnt  = (int)s_bins[bstar];
        pref = (pref << 8) | (unsigned)bstar;
        shift -= 8;
        need -= G;
        gt_base += G;
        c = gt_base + bcnt;        // == #{kk : (kk >> shift) >= pref}
        if (c <= CAP) break;
    }

    if (c <= CAP) {
        // ---- gather survivors: (kk >> shift) >= pref ----
        #pragma unroll
        for (int i = 0; i < 64; ++i) {
            unsigned kk; CAND_KEY(i, kk);
            if ((kk >> shift) >= pref) {
                int slot = atomicAdd(&s_cnt, 1);
                s_lf[slot] = kk; s_li[slot] = (i << 10) + tid;
            }
        }
        if (tid < KPP) {
            unsigned kk = fkey(s_nbne[tid] + s_bne[tid]);
            if ((kk >> shift) >= pref) {
                int slot = atomicAdd(&s_cnt, 1);
                s_lf[slot] = kk; s_li[slot] = NEXT_BASE + tid;
            }
        }
        __syncthreads();
    } else {
        // ---- pathological fallback: pref is the exact 32-bit key T; pick `need`
        // smallest-idx ties via 17-bit idx radix select, then gather exactly 32.
        const unsigned T = pref;
        int pp = 0;
        unsigned istar = 0;
        for (int b = 16; b >= 0; --b) {
            int cnt = 0;
            #pragma unroll 8
            for (int i = 0; i < 64; ++i) {
                unsigned kk; CAND_KEY(i, kk);
                unsigned idx = (unsigned)((i << 10) + tid);
                if (kk == T && (idx >> (b+1)) == (istar >> (b+1)) && !((idx >> b) & 1)) cnt++;
            }
            if (tid < KPP) {
                unsigned kk = fkey(s_nbne[tid] + s_bne[tid]);
                unsigned idx = (unsigned)(NEXT_BASE + tid);
                if (kk == T && (idx >> (b+1)) == (istar >> (b+1)) && !((idx >> b) & 1)) cnt++;
            }
            // block sum
            #pragma unroll
            for (int off = 32; off; off >>= 1) cnt += __shfl_xor(cnt, off);
            if (lane == 0) s_part[pp][wid] = cnt;
            __syncthreads();
            int tot = 0;
            #pragma unroll
            for (int q = 0; q < 16; ++q) tot += s_part[pp][q];
            pp ^= 1;
            if (tot >= need) { /* keep bit 0 */ }
            else { need -= tot; istar |= (1u << b); }
        }
        #pragma unroll 8
        for (int i = 0; i < 64; ++i) {
            unsigned kk; CAND_KEY(i, kk);
            unsigned idx = (unsigned)((i << 10) + tid);
            if (kk > T || (kk == T && idx <= istar)) {
                int slot = atomicAdd(&s_cnt, 1);
                s_lf[slot] = kk; s_li[slot] = (int)idx;
            }
        }
        if (tid < KPP) {
            unsigned kk = fkey(s_nbne[tid] + s_bne[tid]);
            unsigned idx = (unsigned)(NEXT_BASE + tid);
            if (kk > T || (kk == T && idx <= istar)) {
                int slot = atomicAdd(&s_cnt, 1);
                s_lf[slot] = kk; s_li[slot] = (int)idx;
            }
        }
        __syncthreads();
        c = WID;
    }
    const int cc = s_cnt;

    // ---- rank-sort survivors: values desc, idx asc; rank<32 wins, rank = position ----
    for (int e = tid; e < cc; e += 1024) {
        unsigned mf = s_lf[e]; unsigned mi = (unsigned)s_li[e];
        int rank = 0;
        for (int j = 0; j < cc; ++j) {
            unsigned f = s_lf[j];
            rank += (f > mf || (f == mf && (unsigned)s_li[j] < mi)) ? 1 : 0;
        }
        if (rank < WID) { s_selidx[rank] = (int)mi; s_selval[rank] = funkey(mf); }
    }
    __syncthreads();

    // ---- epilogue: per-k scalar outputs ----
    if (tid < WID) {
        int k = tid;
        int ind = s_selidx[k];
        bool noext = ind >= NEXT_BASE;
        int src  = noext ? (ind - NEXT_BASE) : (ind >> 11);
        int extk = ind & (VV-1);                 // == src for nonext (65536 % 2048 == 0)
        int plen = ylens[n*KPP + src];
        int lens = plen + (noext ? 0 : 1);
        float nbv = noext ? s_nbne[src] : s_selval[k];
        float bv  = noext ? s_bne[src]  : 0.0f;
        int lastv = noext ? s_last[src] : extk;
        size_t o = (size_t)n*WID + k;
        out[O_LAST  + o] = (float)lastv;
        out[O_LENS  + o] = (float)lens;
        out[O_NB    + o] = nbv;
        out[O_B     + o] = bv;
        out[O_SRC   + o] = (float)src;
        out[O_NOEXT + o] = noext ? 1.0f : 0.0f;
        s_r_src[k] = src; s_r_lens[k] = lens; s_r_ext[k] = extk;
        s_r_noext[k] = noext ? 1 : 0; s_r_last[k] = lastv;
    }
    __syncthreads();

    // ---- fused y_next: out[t][n][k] ----
    for (int id = tid; id < (SS+1)*WID; id += 1024) {
        int t = id >> 5, k = id & 31;
        int src  = s_r_src[k];
        int plen = s_r_lens[k] - (s_r_noext[k] ? 0 : 1);
        float val;
        if (t == plen)   val = (float)s_r_ext[k];
        else if (t < SS) val = (float)yprev[((size_t)t*NB + n)*KPP + src];
        else             val = 0.0f;
        out[(size_t)t*NK + (size_t)n*WID + k] = val;
    }

    // ---- fused next_is_prefix: one thread per (k, j) ----
    {
        int k = tid >> 5, j = tid & 31;
        int src_k = s_r_src[k], src_j = s_r_src[j];
        int no_k  = s_r_noext[k], no_j = s_r_noext[j];
        int lens_k = s_r_lens[k], lens_j = s_r_lens[j];
        int plen_j = lens_j - (no_j ? 0 : 1);
        bool prefix = pip[((size_t)n*KPP + src_k)*KPP + src_j] != 0;
        bool leq    = lens_k <= lens_j;
        int  tstar  = max(lens_k - 1, 0);
        int  tmj;
        if (tstar == plen_j)   tmj = s_r_ext[j];
        else if (tstar < SS)   tmj = yprev[((size_t)tstar*NB + n)*KPP + src_j];
        else                   tmj = 0;
        bool res = prefix && leq && (no_k || (tmj == s_r_ext[k]));
        out[O_PREF + (size_t)n*WID*WID + tid] = res ? 1.0f : 0.0f;
    }
}

extern "C" void kernel_launch(void* const* d_in, const int* in_sizes, int n_in,
                              void* d_out, int out_size, void* d_ws, size_t ws_size,
                              hipStream_t stream) {
    const float* ext    = (const float*)d_in[0];
    const float* nonext = (const float*)d_in[1];
    const float* blank  = (const float*)d_in[2];
    const float* nbp    = (const float*)d_in[3];
    const float* bp     = (const float*)d_in[4];
    const int*   yprev  = (const int*)d_in[5];
    const int*   ylast  = (const int*)d_in[6];
    const int*   ylens  = (const int*)d_in[7];
    const int*   pip    = (const int*)d_in[8];
    float* out = (float*)d_out;

    ctc_fused_kernel<<<NB, 1024, 0, stream>>>(ext, nonext, blank, nbp, bp,
                                              yprev, ylast, ylens, pip, out);
}